// Round 8
// baseline (10030.378 us; speedup 1.0000x reference)
//
#include <hip/hip_runtime.h>
#include <hip/hip_bf16.h>
#include <math.h>

#define D    1024
#define NQ   512
#define NKV  1024
#define BATCH 8
#define NH   16
#define HD   64
#define FFD  4096

static __device__ __forceinline__ float bf2f(__hip_bfloat16 x){ return __bfloat162float(x); }

// Dual-dtype element load (bf16 or f32 storage).
static __device__ __forceinline__ float ldin(const void* p, size_t idx, bool isb){
    return isb ? bf2f(((const __hip_bfloat16*)p)[idx]) : ((const float*)p)[idx];
}

// Per-tensor storage-dtype probe (see r7 notes). bf16 storage: even u16s are real bf16
// elements -> exponent byte in [0x68,0x85]. f32 storage: even u16s are mantissa noise.
static __device__ __forceinline__ bool is_bf16_dev(const void* p){
    const unsigned short* u = (const unsigned short*)p;
    int good = 0;
    for (int i=0;i<64;i++){
        unsigned e = (u[2*i] >> 7) & 0xFFu;
        if (e >= 0x68u && e <= 0x85u) good++;
    }
    return good >= 32;
}

// ---------------- LayerNorm: x harness input (xIsWs=0) or f32 ws (xIsWs=1) ----------------
__global__ __launch_bounds__(256) void ln_kernel(
    const void* __restrict__ x, int xIsWs,
    const void* __restrict__ gamma, const void* __restrict__ beta,
    float* __restrict__ out)
{
    bool xb = xIsWs ? false : is_bf16_dev(x);
    bool gb = is_bf16_dev(gamma);           // beta is all-zero: read with gamma's dtype
    int row = blockIdx.x, t = threadIdx.x;
    __shared__ float red[256];
    __shared__ float stat[2];
    float v[4];
    float s = 0.f;
    #pragma unroll
    for (int i=0;i<4;i++){ v[i] = ldin(x, (size_t)row*D + t + i*256, xb); s += v[i]; }
    red[t] = s; __syncthreads();
    if (t == 0){ float a=0.f; for (int i=0;i<256;i++) a += red[i]; stat[0] = a*(1.f/D); }
    __syncthreads();
    float mu = stat[0];
    float s2 = 0.f;
    #pragma unroll
    for (int i=0;i<4;i++){ float d0=v[i]-mu; s2 += d0*d0; }
    red[t] = s2; __syncthreads();
    if (t == 0){ float a=0.f; for (int i=0;i<256;i++) a += red[i]; stat[1] = rsqrtf(a*(1.f/D)+1e-5f); }
    __syncthreads();
    float rstd = stat[1];
    #pragma unroll
    for (int i=0;i<4;i++){
        int c = t+i*256;
        out[(size_t)row*D+c] = (v[i]-mu)*rstd*ldin(gamma,c,gb) + ldin(beta,c,gb);
    }
}

// ---------------- 16x16-tile GEMM: C[M,N] = A[M,K] * W[N,K]^T + bias (+epilogue) ----------------
// mode: 0 plain, 1 GELU, 2 weight/bias row-offset D (k slice), 3 offset 2D (v slice).
__global__ __launch_bounds__(256) void gemm16_kernel(
    const void* __restrict__ A, int aBf,
    const void* __restrict__ Wt, const void* __restrict__ bias,
    const void* __restrict__ residIn, const float* __restrict__ residF,
    float* __restrict__ Cf, __hip_bfloat16* __restrict__ Cb,
    int M, int N, int K, int mode)
{
    bool wb = is_bf16_dev(Wt);              // bias is all-zero: read with weight's dtype
    bool rb = residIn ? is_bf16_dev(residIn) : false;
    bool ab = aBf != 0;
    size_t wRowOff = (mode==2) ? (size_t)D : (mode==3) ? (size_t)(2*D) : 0;
    __shared__ float sA[16][17];
    __shared__ float sB[16][17];
    int tx = threadIdx.x, ty = threadIdx.y;
    int n = blockIdx.x*16 + tx;
    int m = blockIdx.y*16 + ty;
    float acc = 0.f;
    for (int k0=0; k0<K; k0+=16){
        sA[ty][tx] = ldin(A, (size_t)m*K + k0 + tx, ab);
        sB[ty][tx] = ldin(Wt, (wRowOff + (size_t)(blockIdx.x*16 + ty))*K + k0 + tx, wb);
        __syncthreads();
        #pragma unroll
        for (int kk=0; kk<16; kk++) acc += sA[ty][kk]*sB[tx][kk];
        __syncthreads();
    }
    float vv = acc + ldin(bias, wRowOff + n, wb);
    if (mode == 1) vv = 0.5f*vv*(1.f + erff(vv*0.70710678118654752f));
    size_t idx = (size_t)m*N + n;
    if (residIn) vv += ldin(residIn, idx, rb);
    if (residF)  vv += residF[idx];
    if (Cf) Cf[idx] = vv;
    if (Cb) Cb[idx] = __float2bfloat16(vv);
}

// ---------------- Attention: one block per (qi, b*NH+h) ----------------
__global__ __launch_bounds__(256) void attn_naive_kernel(
    const __hip_bfloat16* __restrict__ q, const __hip_bfloat16* __restrict__ k,
    const __hip_bfloat16* __restrict__ v, const void* __restrict__ mask,
    float* __restrict__ ctx, float* __restrict__ amean)
{
    int qi = blockIdx.x;
    int b  = blockIdx.y >> 4;
    int h  = blockIdx.y & 15;
    int t  = threadIdx.x;
    __shared__ float qh[HD];
    __shared__ float p[NKV];
    __shared__ float red[256];
    __shared__ float stat[2];
    __shared__ int m8s;
    if (t==0) m8s = 0;
    __syncthreads();
    { unsigned int w = ((const unsigned int*)mask)[t]; if (w>1u) atomicOr(&m8s,1); }
    __syncthreads();
    bool m8 = m8s != 0;
    if (t < HD) qh[t] = bf2f(q[((size_t)(b*NQ+qi))*D + h*HD + t]);
    __syncthreads();
    float lmax = -3.0e38f;
    #pragma unroll
    for (int i=0;i<4;i++){
        int kk = t + i*256;
        size_t mi = (size_t)b*NKV + kk;
        int mk = m8 ? (int)((const unsigned char*)mask)[mi] : ((const int*)mask)[mi];
        const __hip_bfloat16* kr = k + ((size_t)(b*NKV+kk))*D + h*HD;
        float dot = 0.f;
        for (int d0=0; d0<HD; d0++) dot += bf2f(kr[d0])*qh[d0];
        float sv = mk ? -1.0e30f : dot*0.125f;
        p[kk] = sv;
        lmax = fmaxf(lmax, sv);
    }
    red[t] = lmax; __syncthreads();
    if (t==0){ float mm=-3.0e38f; for (int i=0;i<256;i++) mm=fmaxf(mm,red[i]); stat[0]=mm; }
    __syncthreads();
    float m = stat[0];
    float lsum=0.f;
    #pragma unroll
    for (int i=0;i<4;i++){
        int kk=t+i*256;
        float e = __expf(p[kk]-m);
        p[kk]=e; lsum+=e;
    }
    red[t]=lsum; __syncthreads();
    if (t==0){ float a=0.f; for (int i=0;i<256;i++) a+=red[i]; stat[1]=1.f/a; }
    __syncthreads();
    float inv = stat[1];
    #pragma unroll
    for (int i=0;i<4;i++){
        int kk=t+i*256;
        atomicAdd(&amean[((size_t)(b*NQ+qi))*NKV + kk], p[kk]*inv*(1.f/NH));
    }
    if (t < HD){
        float acc=0.f;
        const __hip_bfloat16* vc = v + (size_t)b*NKV*D + h*HD + t;
        for (int kk=0; kk<NKV; kk++) acc += p[kk]*bf2f(vc[(size_t)kk*D]);
        ctx[((size_t)(b*NQ+qi))*D + h*HD + t] = acc*inv;
    }
}

// ---------------- helpers ----------------
__global__ __launch_bounds__(256) void zero_kernel(float* __restrict__ p){
    p[(size_t)blockIdx.x*256 + threadIdx.x] = 0.f;
}
__global__ __launch_bounds__(256) void copy_f32_kernel(const float* __restrict__ in, float* __restrict__ out){
    size_t i = (size_t)blockIdx.x*256 + threadIdx.x;
    out[i] = in[i];
}
__global__ __launch_bounds__(256) void fill_f32_kernel(float* __restrict__ p, float val, long n){
    size_t i = (size_t)blockIdx.x*256 + threadIdx.x;
    if ((long)i < n) p[i] = val;
}

extern "C" void kernel_launch(void* const* d_in, const int* in_sizes, int n_in,
                              void* d_out, int out_size, void* d_ws, size_t ws_size,
                              hipStream_t stream)
{
    const void* qryp      = d_in[0];
    const void* kvp       = d_in[1];
    const void* mask      = d_in[2];
    const void* nq_gamma  = d_in[3];
    const void* nq_beta   = d_in[4];
    const void* nkv_gamma = d_in[5];
    const void* nkv_beta  = d_in[6];
    const void* ipw       = d_in[7];
    const void* ipb       = d_in[8];
    const void* out_w     = d_in[9];
    const void* out_b     = d_in[10];
    const void* nffg      = d_in[11];
    const void* nffb      = d_in[12];
    const void* ff1w      = d_in[13];
    const void* ff1b      = d_in[14];
    const void* ff2w      = d_in[15];
    const void* ff2b      = d_in[16];

    float* out_x = (float*)d_out;                       // x: (8,512,1024) f32
    // ---- host-side shape derivation & consistency checks ----
    long Dn  = (n_in > 3)  ? in_sizes[3]  : 0;
    long FFn = (n_in > 14) ? in_sizes[14] : 0;
    long Rq=0, Rkv=0, Nkvd=0, Bd=0, Nqd=0;
    auto derive = [&](long Sq_, long Skv_)->bool{
        if (Dn <= 0 || Sq_ <= 0 || Skv_ <= 0) return false;
        if (Sq_ % Dn || Skv_ % Dn) return false;
        Rq = Sq_/Dn; Rkv = Skv_/Dn;
        long num = (long)out_size - Rq*Dn;
        if (Rq <= 0 || num <= 0 || num % Rq) return false;
        Nkvd = num / Rq;
        if (Nkvd <= 0 || Rkv % Nkvd) return false;
        Bd = Rkv / Nkvd;
        if (Bd <= 0 || Rq % Bd) return false;
        Nqd = Rq / Bd;
        if ((long)in_sizes[2] != Rkv) return false;
        return true;
    };
    int sentinel = 0;
    if (n_in != 17) sentinel = 600;
    else if (!derive(in_sizes[0], in_sizes[1])) sentinel = 300;
    if (!sentinel && !(Dn==1024 && FFn==4096 && Bd==8 && Nqd==512 && Nkvd==1024)) sentinel = 500;
    if (!sentinel && ws_size < ((size_t)104<<20)) sentinel = 400;
    if (sentinel){
        long n = out_size;
        fill_f32_kernel<<<(unsigned)((n+255)/256), 256, 0, stream>>>(out_x, (float)sentinel, n);
        return;
    }

    float* out_attn = out_x + (size_t)BATCH*NQ*D;       // attn_weights: (8,512,1024) f32

    // Workspace map (bytes), peak 104 MB:
    char* Wc = (char*)d_ws;
    float*          q_in  = (float*)(Wc);
    float*          kv_in = (float*)(Wc + ((size_t)16<<20));
    __hip_bfloat16* qb    = (__hip_bfloat16*)(Wc + ((size_t)48<<20));
    __hip_bfloat16* kb    = (__hip_bfloat16*)(Wc + ((size_t)56<<20));
    __hip_bfloat16* vb    = (__hip_bfloat16*)(Wc + ((size_t)72<<20));
    float*          amean = (float*)(Wc + ((size_t)88<<20));
    float*          ctx   = (float*)(Wc);
    float*          x1    = (float*)(Wc + ((size_t)16<<20));
    float*          hln   = (float*)(Wc + ((size_t)32<<20));
    __hip_bfloat16* hge   = (__hip_bfloat16*)(Wc + ((size_t)48<<20));

    // Full pipeline; all d_out writes are FLOAT32.
    ln_kernel<<<BATCH*NQ,  256, 0, stream>>>(qryp, 0, nq_gamma,  nq_beta,  q_in);
    ln_kernel<<<BATCH*NKV, 256, 0, stream>>>(kvp,  0, nkv_gamma, nkv_beta, kv_in);
    gemm16_kernel<<<dim3(64,256), dim3(16,16), 0, stream>>>(q_in,  0, ipw, ipb, nullptr, nullptr, nullptr, qb, 4096, 1024, 1024, 0);
    gemm16_kernel<<<dim3(64,512), dim3(16,16), 0, stream>>>(kv_in, 0, ipw, ipb, nullptr, nullptr, nullptr, kb, 8192, 1024, 1024, 2);
    gemm16_kernel<<<dim3(64,512), dim3(16,16), 0, stream>>>(kv_in, 0, ipw, ipb, nullptr, nullptr, nullptr, vb, 8192, 1024, 1024, 3);
    zero_kernel<<<16384, 256, 0, stream>>>(amean);
    attn_naive_kernel<<<dim3(NQ, BATCH*NH), 256, 0, stream>>>(qb, kb, vb, mask, ctx, amean);
    copy_f32_kernel<<<16384, 256, 0, stream>>>(amean, out_attn);
    gemm16_kernel<<<dim3(64,256), dim3(16,16), 0, stream>>>(ctx, 0, out_w, out_b, qryp, nullptr, x1, nullptr, 4096, 1024, 1024, 0);
    ln_kernel<<<4096, 256, 0, stream>>>(x1, 1, nffg, nffb, hln);
    gemm16_kernel<<<dim3(256,256), dim3(16,16), 0, stream>>>(hln, 0, ff1w, ff1b, nullptr, nullptr, nullptr, hge, 4096, 4096, 1024, 1);
    gemm16_kernel<<<dim3(64,256), dim3(16,16), 0, stream>>>(hge, 1, ff2w, ff2b, nullptr, x1, out_x, nullptr, 4096, 1024, 4096, 0);
}

// Round 9
// 2609.280 us; speedup vs baseline: 3.8441x; 3.8441x over previous
//
#include <hip/hip_runtime.h>
#include <hip/hip_bf16.h>
#include <math.h>

#define D    1024
#define NQ   512
#define NKV  1024
#define BATCH 8
#define NH   16
#define HD   64
#define FFD  4096

typedef short bf16x8 __attribute__((ext_vector_type(8)));   // 8 bf16 (4 VGPRs)
typedef float f32x4  __attribute__((ext_vector_type(4)));

static __device__ __forceinline__ float bf2f(__hip_bfloat16 x){ return __bfloat162float(x); }
static __device__ __forceinline__ unsigned short f2bbits(float f){
    __hip_bfloat16 h = __float2bfloat16(f);
    return *(unsigned short*)&h;
}

// ---------------- f32 -> bf16 weight conversion ----------------
__global__ __launch_bounds__(256) void cvt_w_kernel(const float* __restrict__ in,
                                                    __hip_bfloat16* __restrict__ out, int n)
{
    int i = blockIdx.x*256 + threadIdx.x;
    if (i < n) out[i] = __float2bfloat16(in[i]);
}

// ---------------- LayerNorm (f32 in -> bf16 out), 256 thr, row = 1024 ----------------
__global__ __launch_bounds__(256) void ln_kernel(
    const float* __restrict__ x, const float* __restrict__ gamma, const float* __restrict__ beta,
    __hip_bfloat16* __restrict__ out)
{
    int row = blockIdx.x, t = threadIdx.x;
    __shared__ float wsum[4];
    __shared__ float stat[2];
    float4 v = *(const float4*)&x[(size_t)row*D + t*4];
    float s = v.x+v.y+v.z+v.w;
    #pragma unroll
    for (int o=32;o>0;o>>=1) s += __shfl_down(s, o);
    if ((t&63)==0) wsum[t>>6] = s;
    __syncthreads();
    if (t==0) stat[0] = (wsum[0]+wsum[1]+wsum[2]+wsum[3])*(1.f/D);
    __syncthreads();
    float mu = stat[0];
    float d0=v.x-mu, d1=v.y-mu, d2=v.z-mu, d3=v.w-mu;
    float s2 = d0*d0+d1*d1+d2*d2+d3*d3;
    #pragma unroll
    for (int o=32;o>0;o>>=1) s2 += __shfl_down(s2, o);
    if ((t&63)==0) wsum[t>>6] = s2;
    __syncthreads();
    if (t==0) stat[1] = rsqrtf((wsum[0]+wsum[1]+wsum[2]+wsum[3])*(1.f/D) + 1e-5f);
    __syncthreads();
    float rs = stat[1];
    const float4 g = *(const float4*)&gamma[t*4];
    const float4 b = *(const float4*)&beta[t*4];
    union { unsigned short u[4]; short4 s4; } pk;
    pk.u[0]=f2bbits(d0*rs*g.x+b.x); pk.u[1]=f2bbits(d1*rs*g.y+b.y);
    pk.u[2]=f2bbits(d2*rs*g.z+b.z); pk.u[3]=f2bbits(d3*rs*g.w+b.w);
    *(short4*)&out[(size_t)row*D + t*4] = pk.s4;
}

// ---------------- MFMA GEMM: C[M,N] = A[M,K](bf16) * Wb[N,K](bf16)^T + bias (+epilogue) ----
// 128x128 tile, BK=32, 4 waves, each 64x64 via 4x4 mfma_f32_16x16x32_bf16.
// bias: f32 (may be null-like zeros); residIn: f32 input; residF: f32 ws; Cf/Cb: f32/bf16 out.
#define BM 128
#define BN 128
#define BK 32
#define LDK 40   // padded LDS row stride (elements) to break bank-conflict strides
__global__ __launch_bounds__(256) void gemm_mfma_kernel(
    const __hip_bfloat16* __restrict__ A, const __hip_bfloat16* __restrict__ Wb,
    const float* __restrict__ bias, int biasOff,
    const float* __restrict__ residIn, const float* __restrict__ residF,
    float* __restrict__ Cf, __hip_bfloat16* __restrict__ Cb,
    int M, int N, int K, int gelu)
{
    __shared__ __hip_bfloat16 As[BM*LDK];
    __shared__ __hip_bfloat16 Bs[BN*LDK];
    int t = threadIdx.x;
    int w = t >> 6, lane = t & 63;
    int quad = lane >> 4, l16 = lane & 15;
    int bm = blockIdx.y * BM, bn = blockIdx.x * BN;
    int wm = (w >> 1) * 64, wn = (w & 1) * 64;
    f32x4 acc[4][4];
    #pragma unroll
    for (int i=0;i<4;i++)
        #pragma unroll
        for (int j=0;j<4;j++) acc[i][j] = (f32x4){0.f,0.f,0.f,0.f};

    for (int k0 = 0; k0 < K; k0 += BK){
        // stage 128x32 A and B tiles; each thread 2 chunks of 8 elems per tile
        #pragma unroll
        for (int rep = 0; rep < 2; rep++){
            int ci = t + rep*256;             // 0..511
            int r = ci >> 2, c = (ci & 3) << 3;
            *(bf16x8*)&As[r*LDK + c] = *(const bf16x8*)&A [(size_t)(bm + r)*K + k0 + c];
            *(bf16x8*)&Bs[r*LDK + c] = *(const bf16x8*)&Wb[(size_t)(bn + r)*K + k0 + c];
        }
        __syncthreads();
        bf16x8 af[4], bfr[4];
        #pragma unroll
        for (int i=0;i<4;i++) af[i]  = *(const bf16x8*)&As[(wm + 16*i + l16)*LDK + quad*8];
        #pragma unroll
        for (int j=0;j<4;j++) bfr[j] = *(const bf16x8*)&Bs[(wn + 16*j + l16)*LDK + quad*8];
        #pragma unroll
        for (int i=0;i<4;i++)
            #pragma unroll
            for (int j=0;j<4;j++)
                acc[i][j] = __builtin_amdgcn_mfma_f32_16x16x32_bf16(af[i], bfr[j], acc[i][j], 0, 0, 0);
        __syncthreads();
    }
    // epilogue: C/D layout col = lane&15, row = quad*4 + reg   [m89-verified]
    #pragma unroll
    for (int i=0;i<4;i++){
        #pragma unroll
        for (int j=0;j<4;j++){
            int colg = bn + wn + 16*j + l16;
            #pragma unroll
            for (int r=0;r<4;r++){
                int rowg = bm + wm + 16*i + quad*4 + r;
                float vv = acc[i][j][r] + bias[biasOff + colg];
                if (gelu) vv = 0.5f*vv*(1.f + erff(vv*0.70710678118654752f));
                size_t idx = (size_t)rowg*N + colg;
                if (residIn) vv += residIn[idx];
                if (residF)  vv += residF[idx];
                if (Cf) Cf[idx] = vv;
                if (Cb) Cb[idx] = __float2bfloat16(vv);
            }
        }
    }
}

// ---------------- Attention: one block per (qi, b); loops 16 heads ----------------
__global__ __launch_bounds__(256) void attn_kernel(
    const __hip_bfloat16* __restrict__ q, const __hip_bfloat16* __restrict__ k,
    const __hip_bfloat16* __restrict__ v, const void* __restrict__ mask,
    __hip_bfloat16* __restrict__ ctx, float* __restrict__ attn_out)
{
    int qi = blockIdx.x, b = blockIdx.y;
    int t = threadIdx.x;
    __shared__ float qrow[D];
    __shared__ float sc[NKV];
    __shared__ float amean[NKV];
    __shared__ float red[256];
    __shared__ float wsum[4];
    __shared__ float stat[2];
    __shared__ int m8s;
    if (t == 0) m8s = 0;
    __syncthreads();
    { unsigned int wd = ((const unsigned int*)mask)[t]; if (wd > 1u) atomicOr(&m8s, 1); }
    __syncthreads();
    bool m8 = m8s != 0;
    const __hip_bfloat16* qp = q + ((size_t)(b*NQ+qi))*D;
    int msk[4];
    #pragma unroll
    for (int i=0;i<4;i++){
        int c = t + i*256;
        qrow[c] = bf2f(qp[c]);
        amean[c] = 0.f;
        size_t mi = (size_t)b*NKV + c;
        msk[i] = m8 ? (int)((const unsigned char*)mask)[mi] : ((const int*)mask)[mi];
    }
    __syncthreads();
    for (int h=0; h<NH; h++){
        const __hip_bfloat16* kh = k + (size_t)b*NKV*D + h*HD;
        const float* qh = qrow + h*HD;
        float lmax = -3.0e38f;
        #pragma unroll
        for (int i=0;i<4;i++){
            int kk = t + i*256;
            const bf16x8* kp = (const bf16x8*)(kh + (size_t)kk*D);
            float dot = 0.f;
            #pragma unroll
            for (int p=0; p<8; p++){
                bf16x8 kv = kp[p];
                #pragma unroll
                for (int e=0; e<8; e++){
                    unsigned short ub = (unsigned short)kv[e];
                    unsigned int fb = ((unsigned int)ub) << 16;
                    dot += *(float*)&fb * qh[p*8+e];
                }
            }
            float sv = msk[i] ? -1.0e30f : dot*0.125f;
            sc[kk] = sv;
            lmax = fmaxf(lmax, sv);
        }
        #pragma unroll
        for (int o=32;o>0;o>>=1) lmax = fmaxf(lmax, __shfl_down(lmax, o));
        if ((t&63)==0) wsum[t>>6] = lmax;
        __syncthreads();
        if (t==0) stat[0] = fmaxf(fmaxf(wsum[0],wsum[1]), fmaxf(wsum[2],wsum[3]));
        __syncthreads();
        float m = stat[0];
        float lsum = 0.f;
        #pragma unroll
        for (int i=0;i<4;i++){
            int kk = t + i*256;
            float e = __expf(sc[kk]-m);
            sc[kk] = e; lsum += e;
        }
        #pragma unroll
        for (int o=32;o>0;o>>=1) lsum += __shfl_down(lsum, o);
        if ((t&63)==0) wsum[t>>6] = lsum;
        __syncthreads();
        if (t==0) stat[1] = 1.f/(wsum[0]+wsum[1]+wsum[2]+wsum[3]);
        __syncthreads();
        float inv = stat[1];
        #pragma unroll
        for (int i=0;i<4;i++){
            int kk = t + i*256;
            amean[kk] += sc[kk]*inv*(1.f/NH);
        }
        int dd = t & 63, g = t >> 6;
        const __hip_bfloat16* vh = v + (size_t)b*NKV*D + h*HD + dd;
        float acc = 0.f;
        int kbase = g*256;
        #pragma unroll 8
        for (int kk=0; kk<256; kk++)
            acc += sc[kbase+kk] * bf2f(vh[(size_t)(kbase+kk)*D]);
        red[t] = acc;
        __syncthreads();
        if (t < 64){
            float c = (red[t]+red[t+64]+red[t+128]+red[t+192]) * inv;
            ctx[((size_t)(b*NQ+qi))*D + h*HD + t] = __float2bfloat16(c);
        }
        __syncthreads();
    }
    float* ao = attn_out + ((size_t)(b*NQ+qi))*NKV;
    #pragma unroll
    for (int i=0;i<4;i++){ int kk=t+i*256; ao[kk] = amean[kk]; }
}

// ---------------- sentinel fill ----------------
__global__ __launch_bounds__(256) void fill_f32_kernel(float* __restrict__ p, float val, long n){
    size_t i = (size_t)blockIdx.x*256 + threadIdx.x;
    if ((long)i < n) p[i] = val;
}

extern "C" void kernel_launch(void* const* d_in, const int* in_sizes, int n_in,
                              void* d_out, int out_size, void* d_ws, size_t ws_size,
                              hipStream_t stream)
{
    const float* query     = (const float*)d_in[0];
    const float* key_value = (const float*)d_in[1];
    const void*  mask      = d_in[2];
    const float* nq_gamma  = (const float*)d_in[3];
    const float* nq_beta   = (const float*)d_in[4];
    const float* nkv_gamma = (const float*)d_in[5];
    const float* nkv_beta  = (const float*)d_in[6];
    const float* ipw       = (const float*)d_in[7];
    const float* ipb       = (const float*)d_in[8];
    const float* out_w     = (const float*)d_in[9];
    const float* out_b     = (const float*)d_in[10];
    const float* nffg      = (const float*)d_in[11];
    const float* nffb      = (const float*)d_in[12];
    const float* ff1w      = (const float*)d_in[13];
    const float* ff1b      = (const float*)d_in[14];
    const float* ff2w      = (const float*)d_in[15];
    const float* ff2b      = (const float*)d_in[16];

    float* out_x = (float*)d_out;
    // ---- host-side shape checks (proven in r6/r8; keep as guard) ----
    long Dn  = (n_in > 3)  ? in_sizes[3]  : 0;
    long FFn = (n_in > 14) ? in_sizes[14] : 0;
    long Rq=0, Rkv=0, Nkvd=0, Bd=0, Nqd=0;
    auto derive = [&](long Sq_, long Skv_)->bool{
        if (Dn <= 0 || Sq_ <= 0 || Skv_ <= 0) return false;
        if (Sq_ % Dn || Skv_ % Dn) return false;
        Rq = Sq_/Dn; Rkv = Skv_/Dn;
        long num = (long)out_size - Rq*Dn;
        if (Rq <= 0 || num <= 0 || num % Rq) return false;
        Nkvd = num / Rq;
        if (Nkvd <= 0 || Rkv % Nkvd) return false;
        Bd = Rkv / Nkvd;
        if (Bd <= 0 || Rq % Bd) return false;
        Nqd = Rq / Bd;
        if ((long)in_sizes[2] != Rkv) return false;
        return true;
    };
    int sentinel = 0;
    if (n_in != 17) sentinel = 600;
    else if (!derive(in_sizes[0], in_sizes[1])) sentinel = 300;
    if (!sentinel && !(Dn==1024 && FFn==4096 && Bd==8 && Nqd==512 && Nkvd==1024)) sentinel = 500;
    if (!sentinel && ws_size < ((size_t)88<<20)) sentinel = 400;
    if (sentinel){
        long n = out_size;
        fill_f32_kernel<<<(unsigned)((n+255)/256), 256, 0, stream>>>(out_x, (float)sentinel, n);
        return;
    }

    float* out_attn = out_x + (size_t)BATCH*NQ*D;

    // Workspace map (bytes), peak 88 MB, lifetimes checked:
    //  [0,6)   wip bf16 (3M)      live all launch
    //  [6,8)   wout bf16 (1M)     live all launch
    //  [8,16)  wff1 bf16 (4M)     live all launch
    //  [16,24) wff2 bf16 (4M)     live all launch
    //  [24,32) qln bf16  -> dead after qproj   -> ctx bf16 (attn)
    //  [32,48) kvln bf16 -> dead after vproj   -> x1 f32 (outproj)
    //  [48,56) qb bf16   -> dead after attn    -> hln bf16
    //  [56,72) kb bf16   -> dead after attn    -> hge bf16 lower
    //  [72,88) vb bf16   -> dead after attn    -> hge bf16 upper
    char* Wc = (char*)d_ws;
    __hip_bfloat16* wip  = (__hip_bfloat16*)(Wc);
    __hip_bfloat16* wout = (__hip_bfloat16*)(Wc + ((size_t)6<<20));
    __hip_bfloat16* wff1 = (__hip_bfloat16*)(Wc + ((size_t)8<<20));
    __hip_bfloat16* wff2 = (__hip_bfloat16*)(Wc + ((size_t)16<<20));
    __hip_bfloat16* qln  = (__hip_bfloat16*)(Wc + ((size_t)24<<20));
    __hip_bfloat16* kvln = (__hip_bfloat16*)(Wc + ((size_t)32<<20));
    __hip_bfloat16* qb   = (__hip_bfloat16*)(Wc + ((size_t)48<<20));
    __hip_bfloat16* kb   = (__hip_bfloat16*)(Wc + ((size_t)56<<20));
    __hip_bfloat16* vb   = (__hip_bfloat16*)(Wc + ((size_t)72<<20));
    __hip_bfloat16* ctx  = (__hip_bfloat16*)(Wc + ((size_t)24<<20));
    float*          x1   = (float*)(Wc + ((size_t)32<<20));
    __hip_bfloat16* hln  = (__hip_bfloat16*)(Wc + ((size_t)48<<20));
    __hip_bfloat16* hge  = (__hip_bfloat16*)(Wc + ((size_t)56<<20));

    // 0) weight conversion f32->bf16
    cvt_w_kernel<<<(3*1024*1024+255)/256, 256, 0, stream>>>(ipw,  wip,  3*1024*1024);
    cvt_w_kernel<<<(1024*1024+255)/256,   256, 0, stream>>>(out_w, wout, 1024*1024);
    cvt_w_kernel<<<(4*1024*1024+255)/256, 256, 0, stream>>>(ff1w, wff1, 4*1024*1024);
    cvt_w_kernel<<<(4*1024*1024+255)/256, 256, 0, stream>>>(ff2w, wff2, 4*1024*1024);
    // 1) LayerNorms -> bf16
    ln_kernel<<<BATCH*NQ,  256, 0, stream>>>(query,     nq_gamma,  nq_beta,  qln);
    ln_kernel<<<BATCH*NKV, 256, 0, stream>>>(key_value, nkv_gamma, nkv_beta, kvln);
    // 2) QKV projections (MFMA)
    gemm_mfma_kernel<<<dim3(8,32),  256, 0, stream>>>(qln,  wip,             ipb, 0,      nullptr, nullptr, nullptr, qb, 4096, 1024, 1024, 0);
    gemm_mfma_kernel<<<dim3(8,64),  256, 0, stream>>>(kvln, wip + (size_t)D*D,   ipb, D,  nullptr, nullptr, nullptr, kb, 8192, 1024, 1024, 0);
    gemm_mfma_kernel<<<dim3(8,64),  256, 0, stream>>>(kvln, wip + (size_t)2*D*D, ipb, 2*D,nullptr, nullptr, nullptr, vb, 8192, 1024, 1024, 0);
    // 3) Attention (ctx bf16, head-mean f32 direct to out)
    attn_kernel<<<dim3(NQ,BATCH), 256, 0, stream>>>(qb, kb, vb, mask, ctx, out_attn);
    // 4) Output projection + residual(query) -> x1 f32
    gemm_mfma_kernel<<<dim3(8,32),  256, 0, stream>>>(ctx, wout, out_b, 0, query, nullptr, x1, nullptr, 4096, 1024, 1024, 0);
    // 5) FFN LN -> hln bf16
    ln_kernel<<<4096, 256, 0, stream>>>(x1, nffg, nffb, hln);
    // 6) FF1 + GELU -> hge bf16
    gemm_mfma_kernel<<<dim3(32,32), 256, 0, stream>>>(hln, wff1, ff1b, 0, nullptr, nullptr, nullptr, hge, 4096, 4096, 1024, 1);
    // 7) FF2 + residual(x1) -> out_x f32
    gemm_mfma_kernel<<<dim3(8,32),  256, 0, stream>>>(hge, wff2, ff2b, 0, nullptr, x1, out_x, nullptr, 4096, 1024, 4096, 0);
}